// Round 13
// baseline (299.155 us; speedup 1.0000x reference)
//
#include <hip/hip_runtime.h>
#include <hip/hip_cooperative_groups.h>

namespace cg = cooperative_groups;

// ---------------------------------------------------------------------------
// GAT 3-layer forward. bf16 MFMA GEMMs with attn coefficients fused into all
// GEMM epilogues. CSR pull aggregation with fused edge-softmax; edges padded
// x4 (sentinel src=Nn, el=-1e9 -> exp=+0). Agg loop: int4 index load + flat
// 4-edge group + packed f32 math (agg is L3-fabric-bound at ~2.8 TB/s fill =
// its floor, invariant across 5 structural variants R5-R12).
// R13: ALL preprocessing (input cvt, weight transposes, zeroing, sentinels)
// + the full CSR build (hist -> scan -> scatter) run in ONE cooperative
// kernel with grid.sync() phases -> 7 launches total (was 12).
// No float atomics, no hipMemsetAsync in the timed path.
// ---------------------------------------------------------------------------

typedef __attribute__((ext_vector_type(8))) short short8;
typedef __attribute__((ext_vector_type(4))) float f32x4;
typedef __attribute__((ext_vector_type(2))) float f32x2;

__device__ __forceinline__ float bf2f(ushort u) {
  union { unsigned int i; float f; } c;
  c.i = ((unsigned int)u) << 16;
  return c.f;
}
__device__ __forceinline__ ushort f2bf(float f) {
  union { float f; unsigned int i; } c;
  c.f = f;
  unsigned int u = c.i;
  u += 0x7FFFu + ((u >> 16) & 1u);
  return (ushort)(u >> 16);
}
__device__ __forceinline__ f32x2 bfp2(uint u) {
  union { unsigned int i; float f; } lo, hi;
  lo.i = u << 16;
  hi.i = u & 0xFFFF0000u;
  f32x2 r;
  r[0] = lo.f;
  r[1] = hi.f;
  return r;
}
__device__ __forceinline__ float lrelu_exp(float x) {
  const float y = fmaxf(x, 0.2f * x);
  return __expf(y);
}
__device__ __forceinline__ void gload_lds16(const ushort* g, void* lds) {
  __builtin_amdgcn_global_load_lds(
      (const __attribute__((address_space(1))) unsigned int*)g,
      (__attribute__((address_space(3))) unsigned int*)lds, 16, 0, 0);
}

__device__ __forceinline__ int block_incl_scan_1024(int x, int* lds16) {
  const int lane = threadIdx.x & 63;
  const int wid = threadIdx.x >> 6;
  int inc = x;
#pragma unroll
  for (int off = 1; off < 64; off <<= 1) {
    const int y = __shfl_up(inc, off);
    if (lane >= off) inc += y;
  }
  if (lane == 63) lds16[wid] = inc;
  __syncthreads();
  if (wid == 0) {
    int t = (lane < 16) ? lds16[lane] : 0;
#pragma unroll
    for (int off = 1; off < 16; off <<= 1) {
      const int y = __shfl_up(t, off);
      if (lane >= off) t += y;
    }
    if (lane < 16) lds16[lane] = t;
  }
  __syncthreads();
  if (wid > 0) inc += lds16[wid - 1];
  return inc;
}

// ---------------- cooperative: prep + CSR build in one launch --------------
// Requires gridDim.x*1024 >= Nn (harness: Nn=50000, we launch 128x1024).
__global__ __launch_bounds__(1024) void csr_coop(
    const float* __restrict__ nf, ushort* __restrict__ a0, int n8,
    const float* __restrict__ W0, ushort* __restrict__ Wt0,
    const float* __restrict__ W1, ushort* __restrict__ Wt1,
    const float* __restrict__ W2, ushort* __restrict__ Wt2,
    const int* __restrict__ src, const int* __restrict__ dst,
    int* __restrict__ cnt, int* __restrict__ row_ptr, int* __restrict__ cursor,
    int* __restrict__ esrc, int* __restrict__ partials,
    float* __restrict__ el4, float* __restrict__ el1,
    ushort* __restrict__ feat_sent, int E, int Nn, int ETP) {
  cg::grid_group grid = cg::this_grid();
  __shared__ int lds16[16];
  const int gtid = blockIdx.x * 1024 + threadIdx.x;
  const int gsz = gridDim.x * 1024;

  // ---- phase 0: cvt input, transpose weights, zero cnt, prefill esrc ----
  for (int i = gtid; i < n8; i += gsz) {
    const float4 v0 = ((const float4*)nf)[i * 2];
    const float4 v1 = ((const float4*)nf)[i * 2 + 1];
    short8 o;
    o[0] = (short)f2bf(v0.x); o[1] = (short)f2bf(v0.y);
    o[2] = (short)f2bf(v0.z); o[3] = (short)f2bf(v0.w);
    o[4] = (short)f2bf(v1.x); o[5] = (short)f2bf(v1.y);
    o[6] = (short)f2bf(v1.z); o[7] = (short)f2bf(v1.w);
    ((short8*)a0)[i] = o;
  }
  for (int i = gtid; i < 32768 + 65536 + 16384; i += gsz) {
    if (i < 32768) {  // W0: K=128, N=256
      const int k = i >> 8, n = i & 255;
      Wt0[n * 128 + k] = f2bf(W0[i]);
    } else if (i < 32768 + 65536) {  // W1: K=256, N=256
      const int j = i - 32768;
      const int k = j >> 8, n = j & 255;
      Wt1[n * 256 + k] = f2bf(W1[j]);
    } else {  // W2: K=256, N=64
      const int j = i - 32768 - 65536;
      const int k = j >> 6, n = j & 63;
      Wt2[n * 256 + k] = f2bf(W2[j]);
    }
  }
  for (int i = gtid; i < Nn; i += gsz) cnt[i] = 0;
  for (int i = gtid; i < ETP; i += gsz) esrc[i] = Nn;
  if (gtid < 4) el4[(size_t)Nn * 4 + gtid] = -1e9f;
  if (gtid == 4) el1[Nn] = -1e9f;
  if (gtid >= 64 && gtid < 192) ((uint*)feat_sent)[gtid - 64] = 0u;
  grid.sync();

  // ---- phase 1: histogram over dst (+self loops) ----
  const int ET = E + Nn;
  for (int e = gtid; e < ET; e += gsz) {
    const int d = (e < E) ? dst[e] : (e - E);
    atomicAdd(&cnt[d], 1);
  }
  grid.sync();

  // ---- phase 2a: block-local scan of padded counts (single tile) ----
  const int x = (gtid < Nn) ? ((cnt[gtid] + 3) & ~3) : 0;
  const int inc = block_incl_scan_1024(x, lds16);
  if (gtid < Nn) row_ptr[gtid] = inc - x;
  if (threadIdx.x == 1023) partials[blockIdx.x] = inc;
  grid.sync();

  // ---- phase 2b: block 0 scans the block partials ----
  if (blockIdx.x == 0) {
    const int nbk = gridDim.x;
    const int xx = (threadIdx.x < nbk) ? partials[threadIdx.x] : 0;
    const int inc2 = block_incl_scan_1024(xx, lds16);
    if (threadIdx.x < nbk) partials[threadIdx.x] = inc2 - xx;
    if (threadIdx.x == nbk - 1) row_ptr[Nn] = inc2;
  }
  grid.sync();

  // ---- phase 2c: add block offsets, init cursor ----
  if (gtid < Nn) {
    const int v = row_ptr[gtid] + partials[blockIdx.x];
    row_ptr[gtid] = v;
    cursor[gtid] = v;
  }
  grid.sync();

  // ---- phase 3: scatter ----
  for (int e = gtid; e < ET; e += gsz) {
    const int s = (e < E) ? src[e] : (e - E);
    const int d = (e < E) ? dst[e] : (e - E);
    esrc[atomicAdd(&cursor[d], 1)] = s;
  }
}

// --------------------- bf16 GEMM, H=4 layers (BM=64, BN=256) ---------------
__global__ __launch_bounds__(256) void gemm_h4(
    const ushort* __restrict__ A, const ushort* __restrict__ Wt,
    ushort* __restrict__ C, int M, int K, const float* __restrict__ al,
    const float* __restrict__ ar, float* __restrict__ el,
    float* __restrict__ er) {
  __shared__ ushort As[64][64];
  __shared__ ushort Bs[256][64];
  const int bm = blockIdx.x * 64;
  const int tid = threadIdx.x;
  const int lane = tid & 63;
  const int wave = tid >> 6;  // == head
  const int lrow = lane >> 3;
  const int lslot = lane & 7;

  f32x4 acc[4][4];
#pragma unroll
  for (int m = 0; m < 4; ++m)
#pragma unroll
    for (int n = 0; n < 4; ++n) acc[m][n] = 0.f;

  for (int k0 = 0; k0 < K; k0 += 64) {
#pragma unroll
    for (int j = 0; j < 2; ++j) {
      const int c = wave * 2 + j;
      const int row = c * 8 + lrow;
      int rg = bm + row;
      if (rg >= M) rg = M - 1;
      const int kcol = (lslot ^ (row & 7)) * 8;
      gload_lds16(A + (size_t)rg * K + k0 + kcol,
                  (char*)(&As[0][0]) + c * 1024 + lrow * 128 + lslot * 16);
    }
#pragma unroll
    for (int j = 0; j < 8; ++j) {
      const int c = wave * 8 + j;
      const int row = c * 8 + lrow;
      const int kcol = (lslot ^ (row & 7)) * 8;
      gload_lds16(Wt + (size_t)row * K + k0 + kcol,
                  (char*)(&Bs[0][0]) + c * 1024 + lrow * 128 + lslot * 16);
    }
    __syncthreads();

#pragma unroll
    for (int kk = 0; kk < 2; ++kk) {
      short8 a[4], b[4];
#pragma unroll
      for (int m = 0; m < 4; ++m) {
        const int row = m * 16 + (lane & 15);
        const int slot = (kk * 4 + (lane >> 4)) ^ (row & 7);
        a[m] = *(const short8*)((const char*)&As[0][0] + row * 128 + slot * 16);
      }
#pragma unroll
      for (int n = 0; n < 4; ++n) {
        const int row = wave * 64 + n * 16 + (lane & 15);
        const int slot = (kk * 4 + (lane >> 4)) ^ (row & 7);
        b[n] = *(const short8*)((const char*)&Bs[0][0] + row * 128 + slot * 16);
      }
#pragma unroll
      for (int m = 0; m < 4; ++m)
#pragma unroll
        for (int n = 0; n < 4; ++n)
          acc[m][n] = __builtin_amdgcn_mfma_f32_16x16x32_bf16(
              a[m], b[n], acc[m][n], 0, 0, 0);
    }
    __syncthreads();
  }

  const int cc = lane & 15;
  float alv[4], arv[4];
#pragma unroll
  for (int n = 0; n < 4; ++n) {
    alv[n] = al[wave * 64 + n * 16 + cc];
    arv[n] = ar[wave * 64 + n * 16 + cc];
  }
#pragma unroll
  for (int m = 0; m < 4; ++m) {
#pragma unroll
    for (int r = 0; r < 4; ++r) {
      const int row = bm + m * 16 + (lane >> 4) * 4 + r;
      const bool ok = row < M;
      if (ok) {
#pragma unroll
        for (int n = 0; n < 4; ++n) {
          const int col = wave * 64 + n * 16 + cc;
          C[(size_t)row * 256 + col] = f2bf(acc[m][n][r]);
        }
      }
      float pl = 0.f, pr = 0.f;
#pragma unroll
      for (int n = 0; n < 4; ++n) {
        pl = fmaf(acc[m][n][r], alv[n], pl);
        pr = fmaf(acc[m][n][r], arv[n], pr);
      }
#pragma unroll
      for (int o = 1; o < 16; o <<= 1) {
        pl += __shfl_xor(pl, o);
        pr += __shfl_xor(pr, o);
      }
      if (cc == 0 && ok) {
        el[row * 4 + wave] = pl;
        er[row * 4 + wave] = pr;
      }
    }
  }
}

// --------------------- bf16 GEMM, H=1 layer (BM=128, BN=64) ----------------
__global__ __launch_bounds__(256) void gemm_h1(
    const ushort* __restrict__ A, const ushort* __restrict__ Wt,
    ushort* __restrict__ C, int M, int K, const float* __restrict__ al,
    const float* __restrict__ ar, float* __restrict__ el,
    float* __restrict__ er) {
  constexpr int NF = 2, NCHB = 8;
  __shared__ ushort As[128][64];
  __shared__ ushort Bs[64][64];
  const int bm = blockIdx.x * 128;
  const int tid = threadIdx.x;
  const int lane = tid & 63;
  const int wave = tid >> 6;
  const int wm = wave >> 1;
  const int wn = wave & 1;
  const int lrow = lane >> 3;
  const int lslot = lane & 7;

  f32x4 acc[4][NF];
#pragma unroll
  for (int m = 0; m < 4; ++m)
#pragma unroll
    for (int n = 0; n < NF; ++n) acc[m][n] = 0.f;

  for (int k0 = 0; k0 < K; k0 += 64) {
#pragma unroll
    for (int c = wave; c < 16; c += 4) {
      const int row = c * 8 + lrow;
      int rg = bm + row;
      if (rg >= M) rg = M - 1;
      const int kcol = (lslot ^ (row & 7)) * 8;
      gload_lds16(A + (size_t)rg * K + k0 + kcol,
                  (char*)(&As[0][0]) + c * 1024 + lrow * 128 + lslot * 16);
    }
#pragma unroll
    for (int c = wave; c < NCHB; c += 4) {
      const int row = c * 8 + lrow;
      const int kcol = (lslot ^ (row & 7)) * 8;
      gload_lds16(Wt + (size_t)row * K + k0 + kcol,
                  (char*)(&Bs[0][0]) + c * 1024 + lrow * 128 + lslot * 16);
    }
    __syncthreads();

#pragma unroll
    for (int kk = 0; kk < 2; ++kk) {
      short8 a[4], b[NF];
#pragma unroll
      for (int m = 0; m < 4; ++m) {
        const int row = wm * 64 + m * 16 + (lane & 15);
        const int slot = (kk * 4 + (lane >> 4)) ^ (row & 7);
        a[m] = *(const short8*)((const char*)&As[0][0] + row * 128 + slot * 16);
      }
#pragma unroll
      for (int n = 0; n < NF; ++n) {
        const int row = wn * 32 + n * 16 + (lane & 15);
        const int slot = (kk * 4 + (lane >> 4)) ^ (row & 7);
        b[n] = *(const short8*)((const char*)&Bs[0][0] + row * 128 + slot * 16);
      }
#pragma unroll
      for (int m = 0; m < 4; ++m)
#pragma unroll
        for (int n = 0; n < NF; ++n)
          acc[m][n] = __builtin_amdgcn_mfma_f32_16x16x32_bf16(
              a[m], b[n], acc[m][n], 0, 0, 0);
    }
    __syncthreads();
  }

#pragma unroll
  for (int m = 0; m < 4; ++m) {
#pragma unroll
    for (int r = 0; r < 4; ++r) {
      const int row = bm + wm * 64 + m * 16 + (lane >> 4) * 4 + r;
      if (row < M) {
#pragma unroll
        for (int n = 0; n < NF; ++n) {
          const int col = wn * 32 + n * 16 + (lane & 15);
          C[(size_t)row * 64 + col] = f2bf(acc[m][n][r]);
        }
      }
    }
  }

  float* red = (float*)&As[0][0];
  const int cc = lane & 15;
  const int q = lane >> 4;
  float alv[NF], arv[NF];
#pragma unroll
  for (int n = 0; n < NF; ++n) {
    alv[n] = al[wn * 32 + n * 16 + cc];
    arv[n] = ar[wn * 32 + n * 16 + cc];
  }
#pragma unroll
  for (int m = 0; m < 4; ++m) {
#pragma unroll
    for (int r = 0; r < 4; ++r) {
      float pl = 0.f, pr = 0.f;
#pragma unroll
      for (int n = 0; n < NF; ++n) {
        pl = fmaf(acc[m][n][r], alv[n], pl);
        pr = fmaf(acc[m][n][r], arv[n], pr);
      }
#pragma unroll
      for (int o = 1; o < 16; o <<= 1) {
        pl += __shfl_xor(pl, o);
        pr += __shfl_xor(pr, o);
      }
      if (cc == 0) {
        const int rl = wm * 64 + m * 16 + q * 4 + r;
        red[rl * 2 + wn] = pl;
        red[256 + rl * 2 + wn] = pr;
      }
    }
  }
  __syncthreads();
  if (tid < 128) {
    const int row = bm + tid;
    if (row < M) {
      el[row] = red[tid * 2] + red[tid * 2 + 1];
      er[row] = red[256 + tid * 2] + red[256 + tid * 2 + 1];
    }
  }
}

// --------------- FUSED softmax + aggregation (pull, no atomics) -----------
__global__ __launch_bounds__(256) void agg_fused_h4(
    const int* __restrict__ row_ptr, const int* __restrict__ esrc,
    const float* __restrict__ el, const float* __restrict__ er,
    const ushort* __restrict__ feat, const float* __restrict__ b,
    ushort* __restrict__ out, int Nn) {
  const int n = (blockIdx.x * 256 + threadIdx.x) >> 6;
  const int lane = threadIdx.x & 63;
  if (n >= Nn) return;
  const int h = lane >> 4;
  const int start = row_ptr[n];
  const int end = row_ptr[n + 1];
  const float erv = er[n * 4 + h];
  const uint2* fb = (const uint2*)feat + lane;

  float den = 0.f;
  f32x2 acc01 = 0.f, acc23 = 0.f;
  for (int i = start; i < end; i += 4) {
    const int4 s = *(const int4*)(esrc + i);
    const float x0 = el[s.x * 4 + h];
    const float x1 = el[s.y * 4 + h];
    const float x2 = el[s.z * 4 + h];
    const float x3 = el[s.w * 4 + h];
    const uint2 f0 = fb[(size_t)s.x * 64];
    const uint2 f1 = fb[(size_t)s.y * 64];
    const uint2 f2 = fb[(size_t)s.z * 64];
    const uint2 f3 = fb[(size_t)s.w * 64];
    const float e0 = lrelu_exp(x0 + erv), e1 = lrelu_exp(x1 + erv),
                e2 = lrelu_exp(x2 + erv), e3 = lrelu_exp(x3 + erv);
    den += (e0 + e1) + (e2 + e3);
    acc01 += bfp2(f0.x) * e0;
    acc23 += bfp2(f0.y) * e0;
    acc01 += bfp2(f1.x) * e1;
    acc23 += bfp2(f1.y) * e1;
    acc01 += bfp2(f2.x) * e2;
    acc23 += bfp2(f2.y) * e2;
    acc01 += bfp2(f3.x) * e3;
    acc23 += bfp2(f3.y) * e3;
  }
  const float rden = 1.f / den;
  const float4 bb = ((const float4*)b)[lane];
  short4 o;
  o.x = (short)f2bf(acc01[0] * rden + bb.x);
  o.y = (short)f2bf(acc01[1] * rden + bb.y);
  o.z = (short)f2bf(acc23[0] * rden + bb.z);
  o.w = (short)f2bf(acc23[1] * rden + bb.w);
  ((short4*)out)[(size_t)n * 64 + lane] = o;
}

__global__ __launch_bounds__(256) void agg_fused_h1(
    const int* __restrict__ row_ptr, const int* __restrict__ esrc,
    const float* __restrict__ el, const float* __restrict__ er,
    const ushort* __restrict__ feat, const float* __restrict__ b,
    float* __restrict__ out, int Nn) {
  const int wid = (blockIdx.x * 256 + threadIdx.x) >> 6;
  const int lane = threadIdx.x & 63;
  const int n = wid * 2 + (lane >> 5);
  const int sub = lane & 31;
  if (n >= Nn) return;
  const int start = row_ptr[n];
  const int end = row_ptr[n + 1];
  const float erv = er[n];
  const uint* fb = (const uint*)feat + sub;

  float den = 0.f;
  f32x2 acc = 0.f;
  for (int i = start; i < end; i += 4) {
    const int4 s = *(const int4*)(esrc + i);
    const float x0 = el[s.x], x1 = el[s.y], x2 = el[s.z], x3 = el[s.w];
    const uint f0 = fb[(size_t)s.x * 32];
    const uint f1 = fb[(size_t)s.y * 32];
    const uint f2 = fb[(size_t)s.z * 32];
    const uint f3 = fb[(size_t)s.w * 32];
    const float e0 = lrelu_exp(x0 + erv), e1 = lrelu_exp(x1 + erv),
                e2 = lrelu_exp(x2 + erv), e3 = lrelu_exp(x3 + erv);
    den += (e0 + e1) + (e2 + e3);
    acc += bfp2(f0) * e0;
    acc += bfp2(f1) * e1;
    acc += bfp2(f2) * e2;
    acc += bfp2(f3) * e3;
  }
  const float rden = 1.f / den;
  const float2 bb = ((const float2*)b)[sub];
  float2 o;
  o.x = acc[0] * rden + bb.x;
  o.y = acc[1] * rden + bb.y;
  ((float2*)out)[(size_t)n * 32 + sub] = o;
}

// ------------------------------- driver -----------------------------------
extern "C" void kernel_launch(void* const* d_in, const int* in_sizes, int n_in,
                              void* d_out, int out_size, void* d_ws,
                              size_t ws_size, hipStream_t stream) {
  const float* nf = (const float*)d_in[0];
  const int* src = (const int*)d_in[1];
  const int* dst = (const int*)d_in[2];
  const float* W0 = (const float*)d_in[3];
  const float* al0 = (const float*)d_in[4];
  const float* ar0 = (const float*)d_in[5];
  const float* b0 = (const float*)d_in[6];
  const float* W1 = (const float*)d_in[7];
  const float* al1 = (const float*)d_in[8];
  const float* ar1 = (const float*)d_in[9];
  const float* b1 = (const float*)d_in[10];
  const float* W2 = (const float*)d_in[11];
  const float* al2 = (const float*)d_in[12];
  const float* ar2 = (const float*)d_in[13];
  const float* b2 = (const float*)d_in[14];

  const int IN = 128;
  const int Nn = in_sizes[0] / IN;
  const int E = in_sizes[1];
  const int ETP = E + 4 * Nn;

  char* ws = (char*)d_ws;
  size_t off = 0;
  auto alloc = [&](size_t bytes) {
    char* p = ws + off;
    off += (bytes + 255) & ~(size_t)255;
    return p;
  };
  ushort* feat = (ushort*)alloc(((size_t)Nn + 1) * 256 * 2);  // +sentinel row
  ushort* h1 = (ushort*)alloc((size_t)Nn * 256 * 2);
  ushort* h2 = (ushort*)alloc((size_t)Nn * 256 * 2);
  ushort* a0 = (ushort*)alloc((size_t)Nn * 128 * 2);
  ushort* Wt0 = (ushort*)alloc((size_t)256 * 128 * 2);
  ushort* Wt1 = (ushort*)alloc((size_t)256 * 256 * 2);
  ushort* Wt2 = (ushort*)alloc((size_t)64 * 256 * 2);
  float* el4 = (float*)alloc(((size_t)Nn + 1) * 4 * 4);
  float* er4 = (float*)alloc((size_t)Nn * 4 * 4);
  float* el1 = (float*)alloc(((size_t)Nn + 1) * 4);
  float* er1 = (float*)alloc((size_t)Nn * 4);
  int* row_ptr = (int*)alloc(((size_t)Nn + 1) * 4);
  int* cnt = (int*)alloc((size_t)Nn * 4);
  int* cursor = (int*)alloc((size_t)Nn * 4);
  int* esrc = (int*)alloc((size_t)ETP * 4);
  int* partials = (int*)alloc((size_t)1024 * 4);
  (void)ws_size;
  (void)n_in;
  (void)out_size;

  // ---- cooperative prep + CSR build (one launch) ----
  {
    int n8 = Nn * 16;
    ushort* feat_sent = feat + (size_t)Nn * 256;
    void* args[] = {&nf, &a0, &n8, &W0, &Wt0, &W1, &Wt1, &W2, &Wt2,
                    &src, &dst, &cnt, &row_ptr, &cursor, &esrc, &partials,
                    &el4, &el1, &feat_sent, (void*)&E, (void*)&Nn,
                    (void*)&ETP};
    int EE = E, NN = Nn, ET = ETP;
    void* args2[] = {&nf, &a0, &n8, &W0, &Wt0, &W1, &Wt1, &W2, &Wt2,
                     &src, &dst, &cnt, &row_ptr, &cursor, &esrc, &partials,
                     &el4, &el1, &feat_sent, &EE, &NN, &ET};
    (void)args;
    hipLaunchCooperativeKernel((const void*)csr_coop, dim3(128), dim3(1024),
                               args2, 0, stream);
  }

  const int waves_grid = (Nn * 64 + 255) / 256;
  const int gemm_grid = (Nn + 63) / 64;

  // Layer 0: [N,128] -> [N,256]  (attn fused into GEMM epilogue)
  gemm_h4<<<gemm_grid, 256, 0, stream>>>(a0, Wt0, feat, Nn, 128, al0, ar0,
                                         el4, er4);
  agg_fused_h4<<<waves_grid, 256, 0, stream>>>(row_ptr, esrc, el4, er4, feat,
                                               b0, h1, Nn);
  // Layer 1: [N,256] -> [N,256]
  gemm_h4<<<gemm_grid, 256, 0, stream>>>(h1, Wt1, feat, Nn, 256, al1, ar1,
                                         el4, er4);
  agg_fused_h4<<<waves_grid, 256, 0, stream>>>(row_ptr, esrc, el4, er4, feat,
                                               b1, h2, Nn);
  // Layer 2: [N,256] -> [N,64]  (attn fused via cross-wave LDS reduce)
  gemm_h1<<<(Nn + 127) / 128, 256, 0, stream>>>(h2, Wt2, feat, Nn, 256, al2,
                                                ar2, el1, er1);
  agg_fused_h1<<<(Nn * 32 + 255) / 256, 256, 0, stream>>>(
      row_ptr, esrc, el1, er1, feat, b2, (float*)d_out, Nn);
}

// Round 14
// 209.283 us; speedup vs baseline: 1.4294x; 1.4294x over previous
//
#include <hip/hip_runtime.h>

// ---------------------------------------------------------------------------
// GAT 3-layer forward. bf16 MFMA GEMMs; H=4 layers use BM=64 x BN=256 blocks
// (A read ONCE per layer; B is L2-resident), attn coefficients fused into all
// GEMM epilogues (H=4: wave==head, shuffle reduce; H=1: cross-wave LDS
// reduce). CSR pull aggregation with fused edge-softmax; edges padded x4
// (sentinel src=Nn, el=-1e9 -> exp=+0, esrc pre-filled in prep). Agg loop:
// int4 index load + flat 4-edge group (TLP > manual ILP; R9 lesson), packed
// f32 channel math. Agg is L3-fabric-bound (~2.8 TB/s L2-fill) = its floor.
// R13 lesson: cooperative-kernel consolidation of prep+CSR REGRESSED 90 us
// (grid.sync barriers + half-machine grid); graph-replay kernel boundaries
// are near-free syncs -- keep separate small kernels.
// No float atomics, no hipMemsetAsync in the timed path.
// ---------------------------------------------------------------------------

typedef __attribute__((ext_vector_type(8))) short short8;
typedef __attribute__((ext_vector_type(4))) float f32x4;
typedef __attribute__((ext_vector_type(2))) float f32x2;
typedef __attribute__((ext_vector_type(4))) int int4v;

__device__ __forceinline__ float bf2f(ushort u) {
  union { unsigned int i; float f; } c;
  c.i = ((unsigned int)u) << 16;
  return c.f;
}
__device__ __forceinline__ ushort f2bf(float f) {
  union { float f; unsigned int i; } c;
  c.f = f;
  unsigned int u = c.i;
  u += 0x7FFFu + ((u >> 16) & 1u);
  return (ushort)(u >> 16);
}
__device__ __forceinline__ f32x2 bfp2(uint u) {
  union { unsigned int i; float f; } lo, hi;
  lo.i = u << 16;
  hi.i = u & 0xFFFF0000u;
  f32x2 r;
  r[0] = lo.f;
  r[1] = hi.f;
  return r;
}
__device__ __forceinline__ float lrelu_exp(float x) {
  const float y = fmaxf(x, 0.2f * x);
  return __expf(y);
}
__device__ __forceinline__ void gload_lds16(const ushort* g, void* lds) {
  __builtin_amdgcn_global_load_lds(
      (const __attribute__((address_space(1))) unsigned int*)g,
      (__attribute__((address_space(3))) unsigned int*)lds, 16, 0, 0);
}

// ------- prep: cvt + weight transposes + zeroing + esrc prefill ------------
__global__ __launch_bounds__(256) void prep_kernel(
    const float* __restrict__ nf, ushort* __restrict__ a0, int n8, int nbA,
    const float* __restrict__ W0, ushort* __restrict__ Wt0,
    const float* __restrict__ W1, ushort* __restrict__ Wt1,
    const float* __restrict__ W2, ushort* __restrict__ Wt2, int nbW,
    int* __restrict__ cnt, int Nn, int nbZ, int* __restrict__ esrc, int ETP,
    int nbE, ushort* __restrict__ feat_sent, float* __restrict__ el4,
    float* __restrict__ el1) {
  const int b = blockIdx.x;
  if (b < nbA) {
    const int i = b * 256 + threadIdx.x;
    if (i >= n8) return;
    const float4 v0 = ((const float4*)nf)[i * 2];
    const float4 v1 = ((const float4*)nf)[i * 2 + 1];
    short8 o;
    o[0] = (short)f2bf(v0.x); o[1] = (short)f2bf(v0.y);
    o[2] = (short)f2bf(v0.z); o[3] = (short)f2bf(v0.w);
    o[4] = (short)f2bf(v1.x); o[5] = (short)f2bf(v1.y);
    o[6] = (short)f2bf(v1.z); o[7] = (short)f2bf(v1.w);
    ((short8*)a0)[i] = o;
  } else if (b < nbA + nbW) {
    const int i = (b - nbA) * 256 + threadIdx.x;
    if (i < 32768) {  // W0: K=128, N=256
      const int k = i >> 8, n = i & 255;
      Wt0[n * 128 + k] = f2bf(W0[i]);
    } else if (i < 32768 + 65536) {  // W1: K=256, N=256
      const int j = i - 32768;
      const int k = j >> 8, n = j & 255;
      Wt1[n * 256 + k] = f2bf(W1[j]);
    } else if (i < 32768 + 65536 + 16384) {  // W2: K=256, N=64
      const int j = i - 32768 - 65536;
      const int k = j >> 6, n = j & 63;
      Wt2[n * 256 + k] = f2bf(W2[j]);
    }
  } else if (b < nbA + nbW + nbZ) {
    const int idx = (b - nbA - nbW) * 256 + threadIdx.x;
    const int base = idx * 4;
    if (base + 4 <= Nn) {
      ((int4v*)cnt)[idx] = (int4v)0;
    } else if (base < Nn) {
      for (int j = base; j < Nn; ++j) cnt[j] = 0;
    }
  } else if (b < nbA + nbW + nbZ + nbE) {
    const int idx = (b - nbA - nbW - nbZ) * 256 + threadIdx.x;
    const int base = idx * 4;
    if (base + 4 <= ETP) {
      ((int4*)esrc)[idx] = make_int4(Nn, Nn, Nn, Nn);
    } else if (base < ETP) {
      for (int j = base; j < ETP; ++j) esrc[j] = Nn;
    }
  } else {
    const int t = threadIdx.x;
    if (t < 128) ((uint*)feat_sent)[t] = 0u;  // 256 ushorts
    if (t >= 128 && t < 132) el4[(size_t)Nn * 4 + (t - 128)] = -1e9f;
    if (t == 132) el1[Nn] = -1e9f;
  }
}

// --------------------- bf16 GEMM, H=4 layers (BM=64, BN=256) ---------------
// A [M][K] bf16, Wt [256][K] bf16 -> C [M][256] bf16. A read once per layer.
// 256 thr = 4 waves; wave w computes rows [bm,bm+64) x cols [w*64,w*64+64)
// == head w. BK=64, XOR source-side swizzle, linear global_load_lds dest.
__global__ __launch_bounds__(256) void gemm_h4(
    const ushort* __restrict__ A, const ushort* __restrict__ Wt,
    ushort* __restrict__ C, int M, int K, const float* __restrict__ al,
    const float* __restrict__ ar, float* __restrict__ el,
    float* __restrict__ er) {
  __shared__ ushort As[64][64];    // 8 KB
  __shared__ ushort Bs[256][64];   // 32 KB
  const int bm = blockIdx.x * 64;
  const int tid = threadIdx.x;
  const int lane = tid & 63;
  const int wave = tid >> 6;  // == head
  const int lrow = lane >> 3;
  const int lslot = lane & 7;

  f32x4 acc[4][4];
#pragma unroll
  for (int m = 0; m < 4; ++m)
#pragma unroll
    for (int n = 0; n < 4; ++n) acc[m][n] = 0.f;

  for (int k0 = 0; k0 < K; k0 += 64) {
#pragma unroll
    for (int j = 0; j < 2; ++j) {
      const int c = wave * 2 + j;
      const int row = c * 8 + lrow;
      int rg = bm + row;
      if (rg >= M) rg = M - 1;
      const int kcol = (lslot ^ (row & 7)) * 8;
      gload_lds16(A + (size_t)rg * K + k0 + kcol,
                  (char*)(&As[0][0]) + c * 1024 + lrow * 128 + lslot * 16);
    }
#pragma unroll
    for (int j = 0; j < 8; ++j) {
      const int c = wave * 8 + j;
      const int row = c * 8 + lrow;  // 0..255
      const int kcol = (lslot ^ (row & 7)) * 8;
      gload_lds16(Wt + (size_t)row * K + k0 + kcol,
                  (char*)(&Bs[0][0]) + c * 1024 + lrow * 128 + lslot * 16);
    }
    __syncthreads();

#pragma unroll
    for (int kk = 0; kk < 2; ++kk) {
      short8 a[4], b[4];
#pragma unroll
      for (int m = 0; m < 4; ++m) {
        const int row = m * 16 + (lane & 15);
        const int slot = (kk * 4 + (lane >> 4)) ^ (row & 7);
        a[m] = *(const short8*)((const char*)&As[0][0] + row * 128 + slot * 16);
      }
#pragma unroll
      for (int n = 0; n < 4; ++n) {
        const int row = wave * 64 + n * 16 + (lane & 15);
        const int slot = (kk * 4 + (lane >> 4)) ^ (row & 7);
        b[n] = *(const short8*)((const char*)&Bs[0][0] + row * 128 + slot * 16);
      }
#pragma unroll
      for (int m = 0; m < 4; ++m)
#pragma unroll
        for (int n = 0; n < 4; ++n)
          acc[m][n] = __builtin_amdgcn_mfma_f32_16x16x32_bf16(
              a[m], b[n], acc[m][n], 0, 0, 0);
    }
    __syncthreads();
  }

  // C write + fused attn (head == wave)
  const int cc = lane & 15;
  float alv[4], arv[4];
#pragma unroll
  for (int n = 0; n < 4; ++n) {
    alv[n] = al[wave * 64 + n * 16 + cc];
    arv[n] = ar[wave * 64 + n * 16 + cc];
  }
#pragma unroll
  for (int m = 0; m < 4; ++m) {
#pragma unroll
    for (int r = 0; r < 4; ++r) {
      const int row = bm + m * 16 + (lane >> 4) * 4 + r;
      const bool ok = row < M;
      if (ok) {
#pragma unroll
        for (int n = 0; n < 4; ++n) {
          const int col = wave * 64 + n * 16 + cc;
          C[(size_t)row * 256 + col] = f2bf(acc[m][n][r]);
        }
      }
      float pl = 0.f, pr = 0.f;
#pragma unroll
      for (int n = 0; n < 4; ++n) {
        pl = fmaf(acc[m][n][r], alv[n], pl);
        pr = fmaf(acc[m][n][r], arv[n], pr);
      }
#pragma unroll
      for (int o = 1; o < 16; o <<= 1) {
        pl += __shfl_xor(pl, o);
        pr += __shfl_xor(pr, o);
      }
      if (cc == 0 && ok) {
        el[row * 4 + wave] = pl;
        er[row * 4 + wave] = pr;
      }
    }
  }
}

// --------------------- bf16 GEMM, H=1 layer (BM=128, BN=64) ----------------
// FUSE: per-wave 32-col partials -> LDS -> combined el1/er1.
__global__ __launch_bounds__(256) void gemm_h1(
    const ushort* __restrict__ A, const ushort* __restrict__ Wt,
    ushort* __restrict__ C, int M, int K, const float* __restrict__ al,
    const float* __restrict__ ar, float* __restrict__ el,
    float* __restrict__ er) {
  constexpr int BN = 64, NF = 2, NCHB = 8;
  __shared__ ushort As[128][64];
  __shared__ ushort Bs[BN][64];
  const int bm = blockIdx.x * 128;
  const int tid = threadIdx.x;
  const int lane = tid & 63;
  const int wave = tid >> 6;
  const int wm = wave >> 1;
  const int wn = wave & 1;
  const int lrow = lane >> 3;
  const int lslot = lane & 7;

  f32x4 acc[4][NF];
#pragma unroll
  for (int m = 0; m < 4; ++m)
#pragma unroll
    for (int n = 0; n < NF; ++n) acc[m][n] = 0.f;

  for (int k0 = 0; k0 < K; k0 += 64) {
#pragma unroll
    for (int c = wave; c < 16; c += 4) {
      const int row = c * 8 + lrow;
      int rg = bm + row;
      if (rg >= M) rg = M - 1;
      const int kcol = (lslot ^ (row & 7)) * 8;
      gload_lds16(A + (size_t)rg * K + k0 + kcol,
                  (char*)(&As[0][0]) + c * 1024 + lrow * 128 + lslot * 16);
    }
#pragma unroll
    for (int c = wave; c < NCHB; c += 4) {
      const int row = c * 8 + lrow;
      const int kcol = (lslot ^ (row & 7)) * 8;
      gload_lds16(Wt + (size_t)row * K + k0 + kcol,
                  (char*)(&Bs[0][0]) + c * 1024 + lrow * 128 + lslot * 16);
    }
    __syncthreads();

#pragma unroll
    for (int kk = 0; kk < 2; ++kk) {
      short8 a[4], b[NF];
#pragma unroll
      for (int m = 0; m < 4; ++m) {
        const int row = wm * 64 + m * 16 + (lane & 15);
        const int slot = (kk * 4 + (lane >> 4)) ^ (row & 7);
        a[m] = *(const short8*)((const char*)&As[0][0] + row * 128 + slot * 16);
      }
#pragma unroll
      for (int n = 0; n < NF; ++n) {
        const int row = wn * 32 + n * 16 + (lane & 15);
        const int slot = (kk * 4 + (lane >> 4)) ^ (row & 7);
        b[n] = *(const short8*)((const char*)&Bs[0][0] + row * 128 + slot * 16);
      }
#pragma unroll
      for (int m = 0; m < 4; ++m)
#pragma unroll
        for (int n = 0; n < NF; ++n)
          acc[m][n] = __builtin_amdgcn_mfma_f32_16x16x32_bf16(
              a[m], b[n], acc[m][n], 0, 0, 0);
    }
    __syncthreads();
  }

#pragma unroll
  for (int m = 0; m < 4; ++m) {
#pragma unroll
    for (int r = 0; r < 4; ++r) {
      const int row = bm + wm * 64 + m * 16 + (lane >> 4) * 4 + r;
      if (row < M) {
#pragma unroll
        for (int n = 0; n < NF; ++n) {
          const int col = wn * 32 + n * 16 + (lane & 15);
          C[(size_t)row * 64 + col] = f2bf(acc[m][n][r]);
        }
      }
    }
  }

  float* red = (float*)&As[0][0];  // [128][2] el, then [128][2] er at +256
  const int cc = lane & 15;
  const int q = lane >> 4;
  float alv[NF], arv[NF];
#pragma unroll
  for (int n = 0; n < NF; ++n) {
    alv[n] = al[wn * 32 + n * 16 + cc];
    arv[n] = ar[wn * 32 + n * 16 + cc];
  }
#pragma unroll
  for (int m = 0; m < 4; ++m) {
#pragma unroll
    for (int r = 0; r < 4; ++r) {
      float pl = 0.f, pr = 0.f;
#pragma unroll
      for (int n = 0; n < NF; ++n) {
        pl = fmaf(acc[m][n][r], alv[n], pl);
        pr = fmaf(acc[m][n][r], arv[n], pr);
      }
#pragma unroll
      for (int o = 1; o < 16; o <<= 1) {
        pl += __shfl_xor(pl, o);
        pr += __shfl_xor(pr, o);
      }
      if (cc == 0) {
        const int rl = wm * 64 + m * 16 + q * 4 + r;
        red[rl * 2 + wn] = pl;
        red[256 + rl * 2 + wn] = pr;
      }
    }
  }
  __syncthreads();
  if (tid < 128) {
    const int row = bm + tid;
    if (row < M) {
      el[row] = red[tid * 2] + red[tid * 2 + 1];
      er[row] = red[256 + tid * 2] + red[256 + tid * 2 + 1];
    }
  }
}

// ------------------------- CSR construction (padded x4) --------------------
__global__ void hist_kernel(const int* __restrict__ dst, int* __restrict__ cnt,
                            int E, int Nn) {
  const int e = blockIdx.x * blockDim.x + threadIdx.x;
  if (e >= E + Nn) return;
  const int d = (e < E) ? dst[e] : (e - E);
  atomicAdd(&cnt[d], 1);
}

__device__ __forceinline__ int block_incl_scan_1024(int x, int* lds16) {
  const int lane = threadIdx.x & 63;
  const int wid = threadIdx.x >> 6;
  int inc = x;
#pragma unroll
  for (int off = 1; off < 64; off <<= 1) {
    const int y = __shfl_up(inc, off);
    if (lane >= off) inc += y;
  }
  if (lane == 63) lds16[wid] = inc;
  __syncthreads();
  if (wid == 0) {
    int t = (lane < 16) ? lds16[lane] : 0;
#pragma unroll
    for (int off = 1; off < 16; off <<= 1) {
      const int y = __shfl_up(t, off);
      if (lane >= off) t += y;
    }
    if (lane < 16) lds16[lane] = t;
  }
  __syncthreads();
  if (wid > 0) inc += lds16[wid - 1];
  return inc;
}

__global__ __launch_bounds__(1024) void scan_blocks_kernel(
    const int* __restrict__ cnt, int* __restrict__ row_ptr,
    int* __restrict__ partials, int n) {
  __shared__ int lds16[16];
  const int i = blockIdx.x * 1024 + threadIdx.x;
  const int x = (i < n) ? ((cnt[i] + 3) & ~3) : 0;
  const int inc = block_incl_scan_1024(x, lds16);
  if (i < n) row_ptr[i] = inc - x;
  if (threadIdx.x == 1023) partials[blockIdx.x] = inc;
}

__global__ __launch_bounds__(1024) void scan_partials_kernel(
    int* __restrict__ partials, int* __restrict__ row_ptr, int nb, int n) {
  __shared__ int lds16[16];
  const int x = (threadIdx.x < nb) ? partials[threadIdx.x] : 0;
  const int inc = block_incl_scan_1024(x, lds16);
  if (threadIdx.x < nb) partials[threadIdx.x] = inc - x;
  if (threadIdx.x == nb - 1) row_ptr[n] = inc;
}

__global__ __launch_bounds__(1024) void add_offsets_kernel(
    int* __restrict__ row_ptr, int* __restrict__ cursor,
    const int* __restrict__ partials, int n) {
  const int i = blockIdx.x * 1024 + threadIdx.x;
  if (i < n) {
    const int v = row_ptr[i] + partials[blockIdx.x];
    row_ptr[i] = v;
    cursor[i] = v;
  }
}

__global__ void scatter_kernel(const int* __restrict__ src,
                               const int* __restrict__ dst,
                               int* __restrict__ cursor, int* __restrict__ esrc,
                               int E, int Nn) {
  const int e = blockIdx.x * blockDim.x + threadIdx.x;
  if (e >= E + Nn) return;
  const int s = (e < E) ? src[e] : (e - E);
  const int d = (e < E) ? dst[e] : (e - E);
  const int pos = atomicAdd(&cursor[d], 1);
  esrc[pos] = s;
}

// --------------- FUSED softmax + aggregation (pull, no atomics) -----------
__global__ __launch_bounds__(256) void agg_fused_h4(
    const int* __restrict__ row_ptr, const int* __restrict__ esrc,
    const float* __restrict__ el, const float* __restrict__ er,
    const ushort* __restrict__ feat, const float* __restrict__ b,
    ushort* __restrict__ out, int Nn) {
  const int n = (blockIdx.x * 256 + threadIdx.x) >> 6;
  const int lane = threadIdx.x & 63;
  if (n >= Nn) return;
  const int h = lane >> 4;
  const int start = row_ptr[n];
  const int end = row_ptr[n + 1];
  const float erv = er[n * 4 + h];
  const uint2* fb = (const uint2*)feat + lane;

  float den = 0.f;
  f32x2 acc01 = 0.f, acc23 = 0.f;
  for (int i = start; i < end; i += 4) {
    const int4 s = *(const int4*)(esrc + i);
    const float x0 = el[s.x * 4 + h];
    const float x1 = el[s.y * 4 + h];
    const float x2 = el[s.z * 4 + h];
    const float x3 = el[s.w * 4 + h];
    const uint2 f0 = fb[(size_t)s.x * 64];
    const uint2 f1 = fb[(size_t)s.y * 64];
    const uint2 f2 = fb[(size_t)s.z * 64];
    const uint2 f3 = fb[(size_t)s.w * 64];
    const float e0 = lrelu_exp(x0 + erv), e1 = lrelu_exp(x1 + erv),
                e2 = lrelu_exp(x2 + erv), e3 = lrelu_exp(x3 + erv);
    den += (e0 + e1) + (e2 + e3);
    acc01 += bfp2(f0.x) * e0;
    acc23 += bfp2(f0.y) * e0;
    acc01 += bfp2(f1.x) * e1;
    acc23 += bfp2(f1.y) * e1;
    acc01 += bfp2(f2.x) * e2;
    acc23 += bfp2(f2.y) * e2;
    acc01 += bfp2(f3.x) * e3;
    acc23 += bfp2(f3.y) * e3;
  }
  const float rden = 1.f / den;
  const float4 bb = ((const float4*)b)[lane];
  short4 o;
  o.x = (short)f2bf(acc01[0] * rden + bb.x);
  o.y = (short)f2bf(acc01[1] * rden + bb.y);
  o.z = (short)f2bf(acc23[0] * rden + bb.z);
  o.w = (short)f2bf(acc23[1] * rden + bb.w);
  ((short4*)out)[(size_t)n * 64 + lane] = o;
}

__global__ __launch_bounds__(256) void agg_fused_h1(
    const int* __restrict__ row_ptr, const int* __restrict__ esrc,
    const float* __restrict__ el, const float* __restrict__ er,
    const ushort* __restrict__ feat, const float* __restrict__ b,
    float* __restrict__ out, int Nn) {
  const int wid = (blockIdx.x * 256 + threadIdx.x) >> 6;
  const int lane = threadIdx.x & 63;
  const int n = wid * 2 + (lane >> 5);
  const int sub = lane & 31;
  if (n >= Nn) return;
  const int start = row_ptr[n];
  const int end = row_ptr[n + 1];
  const float erv = er[n];
  const uint* fb = (const uint*)feat + sub;

  float den = 0.f;
  f32x2 acc = 0.f;
  for (int i = start; i < end; i += 4) {
    const int4 s = *(const int4*)(esrc + i);
    const float x0 = el[s.x], x1 = el[s.y], x2 = el[s.z], x3 = el[s.w];
    const uint f0 = fb[(size_t)s.x * 32];
    const uint f1 = fb[(size_t)s.y * 32];
    const uint f2 = fb[(size_t)s.z * 32];
    const uint f3 = fb[(size_t)s.w * 32];
    const float e0 = lrelu_exp(x0 + erv), e1 = lrelu_exp(x1 + erv),
                e2 = lrelu_exp(x2 + erv), e3 = lrelu_exp(x3 + erv);
    den += (e0 + e1) + (e2 + e3);
    acc += bfp2(f0) * e0;
    acc += bfp2(f1) * e1;
    acc += bfp2(f2) * e2;
    acc += bfp2(f3) * e3;
  }
  const float rden = 1.f / den;
  const float2 bb = ((const float2*)b)[sub];
  float2 o;
  o.x = acc[0] * rden + bb.x;
  o.y = acc[1] * rden + bb.y;
  ((float2*)out)[(size_t)n * 32 + sub] = o;
}

// ------------------------------- driver -----------------------------------
extern "C" void kernel_launch(void* const* d_in, const int* in_sizes, int n_in,
                              void* d_out, int out_size, void* d_ws,
                              size_t ws_size, hipStream_t stream) {
  const float* nf = (const float*)d_in[0];
  const int* src = (const int*)d_in[1];
  const int* dst = (const int*)d_in[2];
  const float* W0 = (const float*)d_in[3];
  const float* al0 = (const float*)d_in[4];
  const float* ar0 = (const float*)d_in[5];
  const float* b0 = (const float*)d_in[6];
  const float* W1 = (const float*)d_in[7];
  const float* al1 = (const float*)d_in[8];
  const float* ar1 = (const float*)d_in[9];
  const float* b1 = (const float*)d_in[10];
  const float* W2 = (const float*)d_in[11];
  const float* al2 = (const float*)d_in[12];
  const float* ar2 = (const float*)d_in[13];
  const float* b2 = (const float*)d_in[14];

  const int IN = 128;
  const int Nn = in_sizes[0] / IN;
  const int E = in_sizes[1];
  const int ETP = E + 4 * Nn;

  char* ws = (char*)d_ws;
  size_t off = 0;
  auto alloc = [&](size_t bytes) {
    char* p = ws + off;
    off += (bytes + 255) & ~(size_t)255;
    return p;
  };
  ushort* feat = (ushort*)alloc(((size_t)Nn + 1) * 256 * 2);  // +sentinel row
  ushort* h1 = (ushort*)alloc((size_t)Nn * 256 * 2);
  ushort* h2 = (ushort*)alloc((size_t)Nn * 256 * 2);
  ushort* a0 = (ushort*)alloc((size_t)Nn * 128 * 2);
  ushort* Wt0 = (ushort*)alloc((size_t)256 * 128 * 2);
  ushort* Wt1 = (ushort*)alloc((size_t)256 * 256 * 2);
  ushort* Wt2 = (ushort*)alloc((size_t)64 * 256 * 2);
  float* el4 = (float*)alloc(((size_t)Nn + 1) * 4 * 4);
  float* er4 = (float*)alloc((size_t)Nn * 4 * 4);
  float* el1 = (float*)alloc(((size_t)Nn + 1) * 4);
  float* er1 = (float*)alloc((size_t)Nn * 4);
  int* row_ptr = (int*)alloc(((size_t)Nn + 1) * 4);
  int* cnt = (int*)alloc((size_t)Nn * 4);
  int* cursor = (int*)alloc((size_t)Nn * 4);
  int* esrc = (int*)alloc((size_t)ETP * 4);
  int* partials = (int*)alloc((size_t)1024 * 4);
  (void)ws_size;
  (void)n_in;
  (void)out_size;

  // prep: cvt + transposes + cnt zero + esrc sentinel prefill + sentinels
  const int n8 = Nn * 16;
  const int nbA = (n8 + 255) / 256;
  const int nbW = (32768 + 65536 + 16384 + 255) / 256;
  const int nbZ = (Nn + 1023) / 1024;
  const int nbE = (ETP + 1023) / 1024;
  prep_kernel<<<nbA + nbW + nbZ + nbE + 1, 256, 0, stream>>>(
      nf, a0, n8, nbA, W0, Wt0, W1, Wt1, W2, Wt2, nbW, cnt, Nn, nbZ, esrc,
      ETP, nbE, feat + (size_t)Nn * 256, el4, el1);

  // ---- Build padded CSR over dst (reused by all 3 layers) ----
  const int ET = E + Nn;
  const int nb = (Nn + 1023) / 1024;
  hist_kernel<<<(ET + 255) / 256, 256, 0, stream>>>(dst, cnt, E, Nn);
  scan_blocks_kernel<<<nb, 1024, 0, stream>>>(cnt, row_ptr, partials, Nn);
  scan_partials_kernel<<<1, 1024, 0, stream>>>(partials, row_ptr, nb, Nn);
  add_offsets_kernel<<<nb, 1024, 0, stream>>>(row_ptr, cursor, partials, Nn);
  scatter_kernel<<<(ET + 255) / 256, 256, 0, stream>>>(src, dst, cursor, esrc,
                                                       E, Nn);

  const int waves_grid = (Nn * 64 + 255) / 256;
  const int gemm_grid = (Nn + 63) / 64;

  // Layer 0: [N,128] -> [N,256]  (attn fused into GEMM epilogue)
  gemm_h4<<<gemm_grid, 256, 0, stream>>>(a0, Wt0, feat, Nn, 128, al0, ar0,
                                         el4, er4);
  agg_fused_h4<<<waves_grid, 256, 0, stream>>>(row_ptr, esrc, el4, er4, feat,
                                               b0, h1, Nn);
  // Layer 1: [N,256] -> [N,256]
  gemm_h4<<<gemm_grid, 256, 0, stream>>>(h1, Wt1, feat, Nn, 256, al1, ar1,
                                         el4, er4);
  agg_fused_h4<<<waves_grid, 256, 0, stream>>>(row_ptr, esrc, el4, er4, feat,
                                               b1, h2, Nn);
  // Layer 2: [N,256] -> [N,64]  (attn fused via cross-wave LDS reduce)
  gemm_h1<<<(Nn + 127) / 128, 256, 0, stream>>>(h2, Wt2, feat, Nn, 256, al2,
                                                ar2, el1, er1);
  agg_fused_h1<<<(Nn * 32 + 255) / 256, 256, 0, stream>>>(
      row_ptr, esrc, el1, er1, feat, b2, (float*)d_out, Nn);
}